// Round 9
// baseline (257.438 us; speedup 1.0000x reference)
//
#include <hip/hip_runtime.h>
#include <hip/hip_bf16.h>

// Problem constants (fixed by the reference)
#define S_LEN 2048
#define NH    16
#define HD    64
#define EMB   1024
#define BATCH 2
#define M_TOT 4096   // B*S

typedef __attribute__((ext_vector_type(8)))  __bf16   bf16x8;
typedef __attribute__((ext_vector_type(4)))  __bf16   bf16x4;
typedef __attribute__((ext_vector_type(4)))  float    f32x4;
typedef __attribute__((ext_vector_type(16))) float    f32x16;
typedef __attribute__((ext_vector_type(4)))  unsigned u32x4;

// pack two f32 -> one u32 of 2 bf16
static __device__ __forceinline__ unsigned pk2(float a, float b) {
    unsigned short ua = __builtin_bit_cast(unsigned short, (__bf16)a);
    unsigned short ub = __builtin_bit_cast(unsigned short, (__bf16)b);
    return (unsigned)ua | ((unsigned)ub << 16);
}

// ---------------------------------------------------------------------------
// One fused fp32->bf16 cast for x + all 4 weights.
// ---------------------------------------------------------------------------
__global__ __launch_bounds__(256) void cast_all(const float* __restrict__ x,
        const float* __restrict__ wq, const float* __restrict__ wk,
        const float* __restrict__ wv, const float* __restrict__ wo,
        __bf16* __restrict__ xb, __bf16* __restrict__ wqb,
        __bf16* __restrict__ wkb, __bf16* __restrict__ wvb,
        __bf16* __restrict__ wob) {
    int i = blockIdx.x * 256 + threadIdx.x;           // 0 .. 2M-1
    const float* src; __bf16* dst; int j;
    if (i < (1 << 20)) { src = x; dst = xb; j = i; }
    else {
        int t = i - (1 << 20);
        int r = t >> 18;                              // 0..3
        j = t & ((1 << 18) - 1);
        src = (r == 0) ? wq : (r == 1) ? wk : (r == 2) ? wv : wo;
        dst = (r == 0) ? wqb : (r == 1) ? wkb : (r == 2) ? wvb : wob;
    }
    f32x4 v = ((const f32x4*)src)[j];
    bf16x4 o;
    o[0] = (__bf16)v[0]; o[1] = (__bf16)v[1];
    o[2] = (__bf16)v[2]; o[3] = (__bf16)v[3];
    ((bf16x4*)dst)[j] = o;
}

// ---------------------------------------------------------------------------
// Fused QKV projection GEMM (m97-style gload_lds staging), unchanged from r6.
// ---------------------------------------------------------------------------
__global__ __launch_bounds__(256) void gemm_qkv(const __bf16* __restrict__ A,
        const __bf16* __restrict__ Wq, const __bf16* __restrict__ Wk,
        const __bf16* __restrict__ Wv,
        const float* __restrict__ bq, const float* __restrict__ bk,
        const float* __restrict__ bv,
        __bf16* __restrict__ Qo, __bf16* __restrict__ Ko, __bf16* __restrict__ Vo) {
    __shared__ __bf16 As[128][64];
    __shared__ __bf16 Bs[128][64];

    const int z = blockIdx.z;
    const __bf16* Bw   = (z == 0) ? Wq : (z == 1) ? Wk : Wv;
    const float*  bias = (z == 0) ? bq : (z == 1) ? bk : bv;
    __bf16*       outp = (z == 0) ? Qo : (z == 1) ? Ko : Vo;

    const int tid  = threadIdx.x;
    const int wid  = tid >> 6;
    const int lane = tid & 63;
    const int lrow = lane & 15;
    const int lhi  = lane >> 4;
    const int m0 = blockIdx.y * 128;
    const int n0 = blockIdx.x * 128;
    const int wr = wid >> 1, wc = wid & 1;

    const int lr8 = lane >> 3;
    const int lc8 = (lane & 7) * 8;

    f32x4 acc[4][4];
#pragma unroll
    for (int i = 0; i < 4; ++i)
#pragma unroll
        for (int j = 0; j < 4; ++j)
            acc[i][j] = (f32x4){0.f, 0.f, 0.f, 0.f};

    for (int k0 = 0; k0 < EMB; k0 += 64) {
#pragma unroll
        for (int t = 0; t < 4; ++t) {
            const int row = wid * 32 + t * 8;
            __builtin_amdgcn_global_load_lds(
                (const __attribute__((address_space(1))) void*)&A[(size_t)(m0 + row + lr8) * EMB + k0 + lc8],
                (__attribute__((address_space(3))) void*)&As[row][0], 16, 0, 0);
            __builtin_amdgcn_global_load_lds(
                (const __attribute__((address_space(1))) void*)&Bw[(size_t)(n0 + row + lr8) * EMB + k0 + lc8],
                (__attribute__((address_space(3))) void*)&Bs[row][0], 16, 0, 0);
        }
        __syncthreads();
#pragma unroll
        for (int kk = 0; kk < 2; ++kk) {
            bf16x8 af[4], bfr[4];
#pragma unroll
            for (int i = 0; i < 4; ++i)
                af[i] = *(const bf16x8*)&As[wr * 64 + i * 16 + lrow][kk * 32 + lhi * 8];
#pragma unroll
            for (int j = 0; j < 4; ++j)
                bfr[j] = *(const bf16x8*)&Bs[wc * 64 + j * 16 + lrow][kk * 32 + lhi * 8];
#pragma unroll
            for (int i = 0; i < 4; ++i)
#pragma unroll
                for (int j = 0; j < 4; ++j)
                    acc[i][j] = __builtin_amdgcn_mfma_f32_16x16x32_bf16(af[i], bfr[j], acc[i][j], 0, 0, 0);
        }
        __syncthreads();
    }

#pragma unroll
    for (int i = 0; i < 4; ++i) {
#pragma unroll
        for (int j = 0; j < 4; ++j) {
#pragma unroll
            for (int jj = 0; jj < 4; ++jj) {
                int row = m0 + wr * 64 + i * 16 + lhi * 4 + jj;   // token b*S+s
                int col = n0 + wc * 64 + j * 16 + lrow;           // feature h*64+d
                float v = acc[i][j][jj] + bias[col];
                int b = row >> 11, s = row & (S_LEN - 1);
                int h = col >> 6,  d = col & (HD - 1);
                size_t idx = (z == 2)
                    ? ((size_t)(b * NH + h) * HD + d) * S_LEN + s     // V^T: [B,H,D,S]
                    : ((size_t)(b * NH + h) * S_LEN + s) * HD + d;    // Q,K: [B,H,S,D]
                outp[idx] = (__bf16)v;
            }
        }
    }
}

// ---------------------------------------------------------------------------
// Output projection: out[4096,1024] fp32 = ctx bf16 @ Wo^T + bo, unchanged.
// ---------------------------------------------------------------------------
__global__ __launch_bounds__(256) void gemm_out(const __bf16* __restrict__ A,
        const __bf16* __restrict__ Bw, const float* __restrict__ bias,
        float* __restrict__ outp) {
    __shared__ __bf16 As[128][64];
    __shared__ __bf16 Bs[128][64];

    const int tid  = threadIdx.x;
    const int wid  = tid >> 6;
    const int lane = tid & 63;
    const int lrow = lane & 15;
    const int lhi  = lane >> 4;
    const int m0 = blockIdx.y * 128;
    const int n0 = blockIdx.x * 128;
    const int wr = wid >> 1, wc = wid & 1;
    const int lr8 = lane >> 3;
    const int lc8 = (lane & 7) * 8;

    f32x4 acc[4][4];
#pragma unroll
    for (int i = 0; i < 4; ++i)
#pragma unroll
        for (int j = 0; j < 4; ++j)
            acc[i][j] = (f32x4){0.f, 0.f, 0.f, 0.f};

    for (int k0 = 0; k0 < EMB; k0 += 64) {
#pragma unroll
        for (int t = 0; t < 4; ++t) {
            const int row = wid * 32 + t * 8;
            __builtin_amdgcn_global_load_lds(
                (const __attribute__((address_space(1))) void*)&A[(size_t)(m0 + row + lr8) * EMB + k0 + lc8],
                (__attribute__((address_space(3))) void*)&As[row][0], 16, 0, 0);
            __builtin_amdgcn_global_load_lds(
                (const __attribute__((address_space(1))) void*)&Bw[(size_t)(n0 + row + lr8) * EMB + k0 + lc8],
                (__attribute__((address_space(3))) void*)&Bs[row][0], 16, 0, 0);
        }
        __syncthreads();
#pragma unroll
        for (int kk = 0; kk < 2; ++kk) {
            bf16x8 af[4], bfr[4];
#pragma unroll
            for (int i = 0; i < 4; ++i)
                af[i] = *(const bf16x8*)&As[wr * 64 + i * 16 + lrow][kk * 32 + lhi * 8];
#pragma unroll
            for (int j = 0; j < 4; ++j)
                bfr[j] = *(const bf16x8*)&Bs[wc * 64 + j * 16 + lrow][kk * 32 + lhi * 8];
#pragma unroll
            for (int i = 0; i < 4; ++i)
#pragma unroll
                for (int j = 0; j < 4; ++j)
                    acc[i][j] = __builtin_amdgcn_mfma_f32_16x16x32_bf16(af[i], bfr[j], acc[i][j], 0, 0, 0);
        }
        __syncthreads();
    }

#pragma unroll
    for (int i = 0; i < 4; ++i)
#pragma unroll
        for (int j = 0; j < 4; ++j)
#pragma unroll
            for (int jj = 0; jj < 4; ++jj) {
                int row = m0 + wr * 64 + i * 16 + lhi * 4 + jj;
                int col = n0 + wc * 64 + j * 16 + lrow;
                outp[(size_t)row * EMB + col] = acc[i][j][jj] + bias[col];
            }
}

// ---------------------------------------------------------------------------
// Flash attention (causal), swapped-QK^T 32x32 in-register softmax.
// v3 (split-K across waves): grid = 2048 blocks, one (qt, bh) per BLOCK; the
// block's 4 waves split the key-tiles (wave w takes kt = w, w+4, ...). Each
// wave keeps its own online-softmax state (m, l, O^T); epilogue merges the 4
// partial states exactly in f32 (flash-decode merge: a_w = exp(m_w - M),
// O = sum a_w O_w, L = sum a_w l_w). Raises resident waves/SIMD ~1 -> ~4 so
// K/V L2 latency + softmax chain overlap across waves (r6: Occupancy 12.4%,
// 3100 cy/iter exposed). Inner loop identical to r6 (passed, absmax 0.0078).
// ---------------------------------------------------------------------------
__global__ __launch_bounds__(256) void attn_kernel(const __bf16* __restrict__ Q,
        const __bf16* __restrict__ K, const __bf16* __restrict__ Vt,
        __bf16* __restrict__ ctx) {
    __shared__ float Of[4][32][65];      // per-wave partial O^T (f32), padded
    __shared__ float MLs[4][2][32];      // per-wave (m, l) per q-row

    const int wid  = threadIdx.x >> 6;
    const int lane = threadIdx.x & 63;
    const int lq   = lane & 31;          // q-column owned by this lane
    const int hi   = lane >> 5;          // half-select
    // decode: xcd = bid&7 keeps all blocks of one bh on one XCD; descending qt
    const int bid  = blockIdx.x;
    const int xcd  = bid & 7;
    const int idx  = bid >> 3;           // 0..255
    const int qt   = 63 - (idx & 63);    // big tiles first (tail drain)
    const int bh   = xcd + 8 * (idx >> 6);   // 0..31
    const int q0   = qt * 32;

    const __bf16* Qh = Q  + (size_t)bh * S_LEN * HD;
    const __bf16* Kh = K  + (size_t)bh * S_LEN * HD;
    const __bf16* Vh = Vt + (size_t)bh * HD * S_LEN;

    // Q B-frag (col=lq, k-elems hi*8..+8 per 16-d slice), pre-scaled by 2^-3
    bf16x8 qf[4];
#pragma unroll
    for (int ds = 0; ds < 4; ++ds) {
        bf16x8 t = *(const bf16x8*)&Qh[(size_t)(q0 + lq) * HD + ds * 16 + hi * 8];
#pragma unroll
        for (int j = 0; j < 8; ++j) qf[ds][j] = (__bf16)((float)t[j] * 0.125f);
    }

    f32x16 o0, o1;                       // O^T accum, d-blocks 0..31 / 32..63
#pragma unroll
    for (int r = 0; r < 16; ++r) { o0[r] = 0.f; o1[r] = 0.f; }
    float m = -1e30f, l = 0.f;

    const int nkt = qt + 1;              // causal: 32-key tiles total

    // prologue: K frags for this wave's first tile (kt = wid)
    bf16x8 kf0, kf1, kf2, kf3;
    if (wid < nkt) {
        const __bf16* kp = &Kh[(size_t)(wid * 32 + lq) * HD + hi * 8];
        kf0 = *(const bf16x8*)(kp);      kf1 = *(const bf16x8*)(kp + 16);
        kf2 = *(const bf16x8*)(kp + 32); kf3 = *(const bf16x8*)(kp + 48);
    }

    for (int kt = wid; kt < nkt; kt += 4) {
        const int kk0 = kt * 32;

        // current V loads (consumed after softmax — latency hidden)
        bf16x8 va0 = *(const bf16x8*)&Vh[(size_t)lq * S_LEN + kk0 + hi * 8];
        bf16x8 vb0 = *(const bf16x8*)&Vh[(size_t)lq * S_LEN + kk0 + 16 + hi * 8];
        bf16x8 va1 = *(const bf16x8*)&Vh[(size_t)(32 + lq) * S_LEN + kk0 + hi * 8];
        bf16x8 vb1 = *(const bf16x8*)&Vh[(size_t)(32 + lq) * S_LEN + kk0 + 16 + hi * 8];

        // prefetch NEXT K tile for this wave (kt+4; clamped on last)
        const int nk0 = (kt + 4 < nkt ? kt + 4 : kt) * 32;
        bf16x8 nkf0, nkf1, nkf2, nkf3;
        {
            const __bf16* kp = &Kh[(size_t)(nk0 + lq) * HD + hi * 8];
            nkf0 = *(const bf16x8*)(kp);      nkf1 = *(const bf16x8*)(kp + 16);
            nkf2 = *(const bf16x8*)(kp + 32); nkf3 = *(const bf16x8*)(kp + 48);
        }

        // QK^T (swapped): S^T = K-frag x Q-frag
        f32x16 s;
#pragma unroll
        for (int r = 0; r < 16; ++r) s[r] = 0.f;
        s = __builtin_amdgcn_mfma_f32_32x32x16_bf16(kf0, qf[0], s, 0, 0, 0);
        s = __builtin_amdgcn_mfma_f32_32x32x16_bf16(kf1, qf[1], s, 0, 0, 0);
        s = __builtin_amdgcn_mfma_f32_32x32x16_bf16(kf2, qf[2], s, 0, 0, 0);
        s = __builtin_amdgcn_mfma_f32_32x32x16_bf16(kf3, qf[3], s, 0, 0, 0);

        // causal mask — only the diagonal tile (wave-uniform branch)
        if (kk0 == q0) {
#pragma unroll
            for (int r = 0; r < 16; ++r) {
                int keyl = (r & 3) + 8 * (r >> 2) + 4 * hi;
                s[r] = (keyl <= lq) ? s[r] : -1e30f;
            }
        }

        // row max: 15 in-lane + cross-half exchange
        float pm = s[0];
#pragma unroll
        for (int r = 1; r < 16; ++r) pm = fmaxf(pm, s[r]);
        pm = fmaxf(pm, __shfl_xor(pm, 32));

        float mn = fmaxf(m, pm);
        float f  = __expf(m - mn);
        m = mn;

        float ps = 0.f;
#pragma unroll
        for (int r = 0; r < 16; ++r) { s[r] = __expf(s[r] - mn); ps += s[r]; }
        ps += __shfl_xor(ps, 32);
        l = l * f + ps;

#pragma unroll
        for (int r = 0; r < 16; ++r) { o0[r] *= f; o1[r] *= f; }

        // pack P to bf16 pairs
        unsigned w0 = pk2(s[0],  s[1]),  w1 = pk2(s[2],  s[3]);
        unsigned w2 = pk2(s[4],  s[5]),  w3 = pk2(s[6],  s[7]);
        unsigned w4 = pk2(s[8],  s[9]),  w5 = pk2(s[10], s[11]);
        unsigned w6 = pk2(s[12], s[13]), w7 = pk2(s[14], s[15]);

        // cross-half redistribution into PV B-frag
        unsigned e0 = (unsigned)__shfl_xor((int)(hi ? w0 : w2), 32);
        unsigned e1 = (unsigned)__shfl_xor((int)(hi ? w1 : w3), 32);
        unsigned e2 = (unsigned)__shfl_xor((int)(hi ? w4 : w6), 32);
        unsigned e3 = (unsigned)__shfl_xor((int)(hi ? w5 : w7), 32);
        u32x4 pb0, pb1;
        if (hi) { pb0 = (u32x4){e0, e1, w2, w3}; pb1 = (u32x4){e2, e3, w6, w7}; }
        else    { pb0 = (u32x4){w0, w1, e0, e1}; pb1 = (u32x4){w4, w5, e2, e3}; }
        bf16x8 pb0b = __builtin_bit_cast(bf16x8, pb0);
        bf16x8 pb1b = __builtin_bit_cast(bf16x8, pb1);

        // PV: O^T[d][q] += V^T[d][k] * P^T[k][q]
        o0 = __builtin_amdgcn_mfma_f32_32x32x16_bf16(va0, pb0b, o0, 0, 0, 0);
        o0 = __builtin_amdgcn_mfma_f32_32x32x16_bf16(vb0, pb1b, o0, 0, 0, 0);
        o1 = __builtin_amdgcn_mfma_f32_32x32x16_bf16(va1, pb0b, o1, 0, 0, 0);
        o1 = __builtin_amdgcn_mfma_f32_32x32x16_bf16(vb1, pb1b, o1, 0, 0, 0);

        kf0 = nkf0; kf1 = nkf1; kf2 = nkf2; kf3 = nkf3;
    }

    // ---- merge the 4 waves' partial states (exact, f32) ----
#pragma unroll
    for (int r = 0; r < 16; ++r) {
        int d0 = (r & 3) + 8 * (r >> 2) + 4 * hi;
        Of[wid][lq][d0]      = o0[r];
        Of[wid][lq][32 + d0] = o1[r];
    }
    if (lane < 32) { MLs[wid][0][lq] = m; MLs[wid][1][lq] = l; }
    __syncthreads();

    // 256 threads: thread t -> q = t>>3, d8 = (t&7)*8 (one bf16x8 store each)
    {
        const int tq = threadIdx.x >> 3;
        const int d8 = (threadIdx.x & 7) * 8;
        float m0_ = MLs[0][0][tq], m1_ = MLs[1][0][tq];
        float m2_ = MLs[2][0][tq], m3_ = MLs[3][0][tq];
        float M = fmaxf(fmaxf(m0_, m1_), fmaxf(m2_, m3_));
        float a0 = __expf(m0_ - M), a1 = __expf(m1_ - M);
        float a2 = __expf(m2_ - M), a3 = __expf(m3_ - M);
        float L = MLs[0][1][tq] * a0 + MLs[1][1][tq] * a1
                + MLs[2][1][tq] * a2 + MLs[3][1][tq] * a3;
        float invL = 1.f / L;
        const int b = bh >> 4, h = bh & 15;
        bf16x8 outv;
#pragma unroll
        for (int e = 0; e < 8; ++e) {
            int d = d8 + e;
            float v = a0 * Of[0][tq][d] + a1 * Of[1][tq][d]
                    + a2 * Of[2][tq][d] + a3 * Of[3][tq][d];
            outv[e] = (__bf16)(v * invL);
        }
        *(bf16x8*)&ctx[((size_t)b * S_LEN + q0 + tq) * EMB + h * HD + d8] = outv;
    }
}

// ---------------------------------------------------------------------------
extern "C" void kernel_launch(void* const* d_in, const int* in_sizes, int n_in,
                              void* d_out, int out_size, void* d_ws, size_t ws_size,
                              hipStream_t stream) {
    const float* x  = (const float*)d_in[0];
    const float* Wq = (const float*)d_in[1];
    const float* bq = (const float*)d_in[2];
    const float* Wk = (const float*)d_in[3];
    const float* bk = (const float*)d_in[4];
    const float* Wv = (const float*)d_in[5];
    const float* bv = (const float*)d_in[6];
    const float* Wo = (const float*)d_in[7];
    const float* bo = (const float*)d_in[8];

    char* ws = (char*)d_ws;
    __bf16* xb  = (__bf16*)(ws);                       // 8 MB  (4M bf16)
    __bf16* Wqb = (__bf16*)(ws + ( 8ull << 20));       // 2 MB
    __bf16* Wkb = (__bf16*)(ws + (10ull << 20));
    __bf16* Wvb = (__bf16*)(ws + (12ull << 20));
    __bf16* Wob = (__bf16*)(ws + (14ull << 20));
    __bf16* Qb  = (__bf16*)(ws + (16ull << 20));       // 8 MB [B,H,S,D]
    __bf16* Kb  = (__bf16*)(ws + (24ull << 20));       // 8 MB [B,H,S,D]
    __bf16* Vtb = (__bf16*)(ws + (32ull << 20));       // 8 MB [B,H,D,S]
    __bf16* Cb  = (__bf16*)(ws + (40ull << 20));       // 8 MB [B,S,E]

    // one fused cast (x + 4 weights)
    cast_all<<<8192, 256, 0, stream>>>(x, Wq, Wk, Wv, Wo, xb, Wqb, Wkb, Wvb, Wob);

    // fused QKV projection (z selects Q/K/V)
    gemm_qkv<<<dim3(EMB / 128, M_TOT / 128, 3), 256, 0, stream>>>(
        xb, Wqb, Wkb, Wvb, bq, bk, bv, Qb, Kb, Vtb);

    // flash attention (split-K across waves + f32 merge, XCD decode)
    attn_kernel<<<dim3(2048), 256, 0, stream>>>(Qb, Kb, Vtb, Cb);

    // output projection (fp32 out + bias)
    gemm_out<<<dim3(EMB / 128, M_TOT / 128), 256, 0, stream>>>(Cb, Wob, bo, (float*)d_out);
}

// Round 10
// 238.752 us; speedup vs baseline: 1.0783x; 1.0783x over previous
//
#include <hip/hip_runtime.h>
#include <hip/hip_bf16.h>

// Problem constants (fixed by the reference)
#define S_LEN 2048
#define NH    16
#define HD    64
#define EMB   1024
#define BATCH 2
#define M_TOT 4096   // B*S

typedef __attribute__((ext_vector_type(8)))  __bf16   bf16x8;
typedef __attribute__((ext_vector_type(4)))  __bf16   bf16x4;
typedef __attribute__((ext_vector_type(4)))  float    f32x4;
typedef __attribute__((ext_vector_type(16))) float    f32x16;
typedef __attribute__((ext_vector_type(4)))  unsigned u32x4;

// pack two f32 -> one u32 of 2 bf16
static __device__ __forceinline__ unsigned pk2(float a, float b) {
    unsigned short ua = __builtin_bit_cast(unsigned short, (__bf16)a);
    unsigned short ub = __builtin_bit_cast(unsigned short, (__bf16)b);
    return (unsigned)ua | ((unsigned)ub << 16);
}

// ---------------------------------------------------------------------------
// One fused fp32->bf16 cast for x + all 4 weights.
// ---------------------------------------------------------------------------
__global__ __launch_bounds__(256) void cast_all(const float* __restrict__ x,
        const float* __restrict__ wq, const float* __restrict__ wk,
        const float* __restrict__ wv, const float* __restrict__ wo,
        __bf16* __restrict__ xb, __bf16* __restrict__ wqb,
        __bf16* __restrict__ wkb, __bf16* __restrict__ wvb,
        __bf16* __restrict__ wob) {
    int i = blockIdx.x * 256 + threadIdx.x;           // 0 .. 2M-1
    const float* src; __bf16* dst; int j;
    if (i < (1 << 20)) { src = x; dst = xb; j = i; }
    else {
        int t = i - (1 << 20);
        int r = t >> 18;                              // 0..3
        j = t & ((1 << 18) - 1);
        src = (r == 0) ? wq : (r == 1) ? wk : (r == 2) ? wv : wo;
        dst = (r == 0) ? wqb : (r == 1) ? wkb : (r == 2) ? wvb : wob;
    }
    f32x4 v = ((const f32x4*)src)[j];
    bf16x4 o;
    o[0] = (__bf16)v[0]; o[1] = (__bf16)v[1];
    o[2] = (__bf16)v[2]; o[3] = (__bf16)v[3];
    ((bf16x4*)dst)[j] = o;
}

// ---------------------------------------------------------------------------
// 2-phase double-buffered GEMM body (T3 minimum-2-phase recipe, m248):
// stage(next K-tile) issued BEFORE compute(current) so global_load_lds
// latency hides under MFMA; ONE barrier per K-tile (syncthreads drains
// vmcnt(0) -> staged buffer complete). Buffers statically indexed via
// 2x-unrolled loop. LDS = 2 x (128x64 A + 128x64 B) bf16 = 64 KB.
// ---------------------------------------------------------------------------
#define GEMM_STAGE(Abuf, Bbuf, Asrc, Bsrc, k0)                                            \
    _Pragma("unroll")                                                                     \
    for (int t = 0; t < 4; ++t) {                                                         \
        const int row = wid * 32 + t * 8;                                                 \
        __builtin_amdgcn_global_load_lds(                                                 \
            (const __attribute__((address_space(1))) void*)&Asrc[(size_t)(m0 + row + lr8) * EMB + (k0) + lc8], \
            (__attribute__((address_space(3))) void*)&Abuf[row][0], 16, 0, 0);            \
        __builtin_amdgcn_global_load_lds(                                                 \
            (const __attribute__((address_space(1))) void*)&Bsrc[(size_t)(n0 + row + lr8) * EMB + (k0) + lc8], \
            (__attribute__((address_space(3))) void*)&Bbuf[row][0], 16, 0, 0);            \
    }

#define GEMM_COMPUTE(Abuf, Bbuf)                                                          \
    _Pragma("unroll")                                                                     \
    for (int kk = 0; kk < 2; ++kk) {                                                      \
        bf16x8 af[4], bfr[4];                                                             \
        _Pragma("unroll")                                                                 \
        for (int i = 0; i < 4; ++i)                                                       \
            af[i] = *(const bf16x8*)&Abuf[wr * 64 + i * 16 + lrow][kk * 32 + lhi * 8];    \
        _Pragma("unroll")                                                                 \
        for (int j = 0; j < 4; ++j)                                                       \
            bfr[j] = *(const bf16x8*)&Bbuf[wc * 64 + j * 16 + lrow][kk * 32 + lhi * 8];   \
        _Pragma("unroll")                                                                 \
        for (int i = 0; i < 4; ++i)                                                       \
            _Pragma("unroll")                                                             \
            for (int j = 0; j < 4; ++j)                                                   \
                acc[i][j] = __builtin_amdgcn_mfma_f32_16x16x32_bf16(af[i], bfr[j], acc[i][j], 0, 0, 0); \
    }

// ---------------------------------------------------------------------------
// Fused QKV projection GEMM. C[4096,1024] = A @ W^T + bias. z selects {Q,K,V}.
// Q,K -> [B,H,S,D]; V -> [B,H,D,S] (transposed) for attention PV A-operand.
// ---------------------------------------------------------------------------
__global__ __launch_bounds__(256) void gemm_qkv(const __bf16* __restrict__ A,
        const __bf16* __restrict__ Wq, const __bf16* __restrict__ Wk,
        const __bf16* __restrict__ Wv,
        const float* __restrict__ bq, const float* __restrict__ bk,
        const float* __restrict__ bv,
        __bf16* __restrict__ Qo, __bf16* __restrict__ Ko, __bf16* __restrict__ Vo) {
    __shared__ __bf16 As0[128][64], As1[128][64];
    __shared__ __bf16 Bs0[128][64], Bs1[128][64];

    const int z = blockIdx.z;
    const __bf16* Bw   = (z == 0) ? Wq : (z == 1) ? Wk : Wv;
    const float*  bias = (z == 0) ? bq : (z == 1) ? bk : bv;
    __bf16*       outp = (z == 0) ? Qo : (z == 1) ? Ko : Vo;

    const int tid  = threadIdx.x;
    const int wid  = tid >> 6;
    const int lane = tid & 63;
    const int lrow = lane & 15;
    const int lhi  = lane >> 4;
    const int m0 = blockIdx.y * 128;
    const int n0 = blockIdx.x * 128;
    const int wr = wid >> 1, wc = wid & 1;
    const int lr8 = lane >> 3;
    const int lc8 = (lane & 7) * 8;

    f32x4 acc[4][4];
#pragma unroll
    for (int i = 0; i < 4; ++i)
#pragma unroll
        for (int j = 0; j < 4; ++j)
            acc[i][j] = (f32x4){0.f, 0.f, 0.f, 0.f};

    GEMM_STAGE(As0, Bs0, A, Bw, 0)
    __syncthreads();
    for (int kt = 0; kt < 16; kt += 2) {
        GEMM_STAGE(As1, Bs1, A, Bw, (kt + 1) * 64)
        GEMM_COMPUTE(As0, Bs0)
        __syncthreads();
        if (kt + 2 < 16) { GEMM_STAGE(As0, Bs0, A, Bw, (kt + 2) * 64) }
        GEMM_COMPUTE(As1, Bs1)
        __syncthreads();
    }

    // Epilogue: C/D layout col = lane&15, row = (lane>>4)*4 + reg  [m89-verified]
#pragma unroll
    for (int i = 0; i < 4; ++i) {
#pragma unroll
        for (int j = 0; j < 4; ++j) {
#pragma unroll
            for (int jj = 0; jj < 4; ++jj) {
                int row = m0 + wr * 64 + i * 16 + lhi * 4 + jj;   // token b*S+s
                int col = n0 + wc * 64 + j * 16 + lrow;           // feature h*64+d
                float v = acc[i][j][jj] + bias[col];
                int b = row >> 11, s = row & (S_LEN - 1);
                int h = col >> 6,  d = col & (HD - 1);
                size_t idx = (z == 2)
                    ? ((size_t)(b * NH + h) * HD + d) * S_LEN + s     // V^T: [B,H,D,S]
                    : ((size_t)(b * NH + h) * S_LEN + s) * HD + d;    // Q,K: [B,H,S,D]
                outp[idx] = (__bf16)v;
            }
        }
    }
}

// ---------------------------------------------------------------------------
// Output projection: out[4096,1024] fp32 = ctx bf16 @ Wo^T + bo (2-phase dbuf)
// ---------------------------------------------------------------------------
__global__ __launch_bounds__(256) void gemm_out(const __bf16* __restrict__ A,
        const __bf16* __restrict__ Bw, const float* __restrict__ bias,
        float* __restrict__ outp) {
    __shared__ __bf16 As0[128][64], As1[128][64];
    __shared__ __bf16 Bs0[128][64], Bs1[128][64];

    const int tid  = threadIdx.x;
    const int wid  = tid >> 6;
    const int lane = tid & 63;
    const int lrow = lane & 15;
    const int lhi  = lane >> 4;
    const int m0 = blockIdx.y * 128;
    const int n0 = blockIdx.x * 128;
    const int wr = wid >> 1, wc = wid & 1;
    const int lr8 = lane >> 3;
    const int lc8 = (lane & 7) * 8;

    f32x4 acc[4][4];
#pragma unroll
    for (int i = 0; i < 4; ++i)
#pragma unroll
        for (int j = 0; j < 4; ++j)
            acc[i][j] = (f32x4){0.f, 0.f, 0.f, 0.f};

    GEMM_STAGE(As0, Bs0, A, Bw, 0)
    __syncthreads();
    for (int kt = 0; kt < 16; kt += 2) {
        GEMM_STAGE(As1, Bs1, A, Bw, (kt + 1) * 64)
        GEMM_COMPUTE(As0, Bs0)
        __syncthreads();
        if (kt + 2 < 16) { GEMM_STAGE(As0, Bs0, A, Bw, (kt + 2) * 64) }
        GEMM_COMPUTE(As1, Bs1)
        __syncthreads();
    }

#pragma unroll
    for (int i = 0; i < 4; ++i)
#pragma unroll
        for (int j = 0; j < 4; ++j)
#pragma unroll
            for (int jj = 0; jj < 4; ++jj) {
                int row = m0 + wr * 64 + i * 16 + lhi * 4 + jj;
                int col = n0 + wc * 64 + j * 16 + lrow;
                outp[(size_t)row * EMB + col] = acc[i][j][jj] + bias[col];
            }
}

// ---------------------------------------------------------------------------
// Flash attention (causal), swapped-QK^T 32x32, split-K across waves (r9 base,
// passed @absmax 0.0078). r10 deltas: (a) T13 defer-max (skip the 32-op O
// rescale + exp when __all(pm - m <= 8); P bounded by e^8, exact algebra via
// l bookkeeping); (b) branchless cndmask P-fragment select (was a divergent
// hi/lo if — both sides executed under exec-masking).
// ---------------------------------------------------------------------------
__global__ __launch_bounds__(256) void attn_kernel(const __bf16* __restrict__ Q,
        const __bf16* __restrict__ K, const __bf16* __restrict__ Vt,
        __bf16* __restrict__ ctx) {
    __shared__ float Of[4][32][65];      // per-wave partial O^T (f32), padded
    __shared__ float MLs[4][2][32];      // per-wave (m, l) per q-row

    const int wid  = threadIdx.x >> 6;
    const int lane = threadIdx.x & 63;
    const int lq   = lane & 31;          // q-column owned by this lane
    const int hi   = lane >> 5;          // half-select
    const int bid  = blockIdx.x;
    const int xcd  = bid & 7;
    const int idx  = bid >> 3;           // 0..255
    const int qt   = 63 - (idx & 63);    // big tiles first (tail drain)
    const int bh   = xcd + 8 * (idx >> 6);   // 0..31
    const int q0   = qt * 32;

    const __bf16* Qh = Q  + (size_t)bh * S_LEN * HD;
    const __bf16* Kh = K  + (size_t)bh * S_LEN * HD;
    const __bf16* Vh = Vt + (size_t)bh * HD * S_LEN;

    // Q B-frag (col=lq, k-elems hi*8..+8 per 16-d slice), pre-scaled by 2^-3
    bf16x8 qf[4];
#pragma unroll
    for (int ds = 0; ds < 4; ++ds) {
        bf16x8 t = *(const bf16x8*)&Qh[(size_t)(q0 + lq) * HD + ds * 16 + hi * 8];
#pragma unroll
        for (int j = 0; j < 8; ++j) qf[ds][j] = (__bf16)((float)t[j] * 0.125f);
    }

    f32x16 o0, o1;                       // O^T accum, d-blocks 0..31 / 32..63
#pragma unroll
    for (int r = 0; r < 16; ++r) { o0[r] = 0.f; o1[r] = 0.f; }
    float m = -1e30f, l = 0.f;

    const int nkt = qt + 1;              // causal: 32-key tiles total

    // prologue: K frags for this wave's first tile (kt = wid)
    bf16x8 kf0, kf1, kf2, kf3;
    if (wid < nkt) {
        const __bf16* kp = &Kh[(size_t)(wid * 32 + lq) * HD + hi * 8];
        kf0 = *(const bf16x8*)(kp);      kf1 = *(const bf16x8*)(kp + 16);
        kf2 = *(const bf16x8*)(kp + 32); kf3 = *(const bf16x8*)(kp + 48);
    }

    for (int kt = wid; kt < nkt; kt += 4) {
        const int kk0 = kt * 32;

        // current V loads (consumed after softmax — latency hidden)
        bf16x8 va0 = *(const bf16x8*)&Vh[(size_t)lq * S_LEN + kk0 + hi * 8];
        bf16x8 vb0 = *(const bf16x8*)&Vh[(size_t)lq * S_LEN + kk0 + 16 + hi * 8];
        bf16x8 va1 = *(const bf16x8*)&Vh[(size_t)(32 + lq) * S_LEN + kk0 + hi * 8];
        bf16x8 vb1 = *(const bf16x8*)&Vh[(size_t)(32 + lq) * S_LEN + kk0 + 16 + hi * 8];

        // prefetch NEXT K tile for this wave (kt+4; clamped on last)
        const int nk0 = (kt + 4 < nkt ? kt + 4 : kt) * 32;
        bf16x8 nkf0, nkf1, nkf2, nkf3;
        {
            const __bf16* kp = &Kh[(size_t)(nk0 + lq) * HD + hi * 8];
            nkf0 = *(const bf16x8*)(kp);      nkf1 = *(const bf16x8*)(kp + 16);
            nkf2 = *(const bf16x8*)(kp + 32); nkf3 = *(const bf16x8*)(kp + 48);
        }

        // QK^T (swapped): S^T = K-frag x Q-frag
        f32x16 s;
#pragma unroll
        for (int r = 0; r < 16; ++r) s[r] = 0.f;
        s = __builtin_amdgcn_mfma_f32_32x32x16_bf16(kf0, qf[0], s, 0, 0, 0);
        s = __builtin_amdgcn_mfma_f32_32x32x16_bf16(kf1, qf[1], s, 0, 0, 0);
        s = __builtin_amdgcn_mfma_f32_32x32x16_bf16(kf2, qf[2], s, 0, 0, 0);
        s = __builtin_amdgcn_mfma_f32_32x32x16_bf16(kf3, qf[3], s, 0, 0, 0);

        // causal mask — only the diagonal tile (wave-uniform branch)
        if (kk0 == q0) {
#pragma unroll
            for (int r = 0; r < 16; ++r) {
                int keyl = (r & 3) + 8 * (r >> 2) + 4 * hi;
                s[r] = (keyl <= lq) ? s[r] : -1e30f;
            }
        }

        // row max: 15 in-lane + cross-half exchange
        float pm = s[0];
#pragma unroll
        for (int r = 1; r < 16; ++r) pm = fmaxf(pm, s[r]);
        pm = fmaxf(pm, __shfl_xor(pm, 32));

        // T13 defer-max: only rescale when running max grew by > 8
        if (!__all(pm - m <= 8.f)) {
            float mn = fmaxf(m, pm);
            float f  = __expf(m - mn);
            l *= f;
#pragma unroll
            for (int r = 0; r < 16; ++r) { o0[r] *= f; o1[r] *= f; }
            m = mn;
        }

        float ps = 0.f;
#pragma unroll
        for (int r = 0; r < 16; ++r) { s[r] = __expf(s[r] - m); ps += s[r]; }
        ps += __shfl_xor(ps, 32);
        l += ps;

        // pack P to bf16 pairs
        unsigned w0 = pk2(s[0],  s[1]),  w1 = pk2(s[2],  s[3]);
        unsigned w2 = pk2(s[4],  s[5]),  w3 = pk2(s[6],  s[7]);
        unsigned w4 = pk2(s[8],  s[9]),  w5 = pk2(s[10], s[11]);
        unsigned w6 = pk2(s[12], s[13]), w7 = pk2(s[14], s[15]);

        // cross-half redistribution into PV B-frag (branchless cndmask)
        unsigned e0 = (unsigned)__shfl_xor((int)(hi ? w0 : w2), 32);
        unsigned e1 = (unsigned)__shfl_xor((int)(hi ? w1 : w3), 32);
        unsigned e2 = (unsigned)__shfl_xor((int)(hi ? w4 : w6), 32);
        unsigned e3 = (unsigned)__shfl_xor((int)(hi ? w5 : w7), 32);
        u32x4 pb0, pb1;
        pb0[0] = hi ? e0 : w0;  pb0[1] = hi ? e1 : w1;
        pb0[2] = hi ? w2 : e0;  pb0[3] = hi ? w3 : e1;
        pb1[0] = hi ? e2 : w4;  pb1[1] = hi ? e3 : w5;
        pb1[2] = hi ? w6 : e2;  pb1[3] = hi ? w7 : e3;
        bf16x8 pb0b = __builtin_bit_cast(bf16x8, pb0);
        bf16x8 pb1b = __builtin_bit_cast(bf16x8, pb1);

        // PV: O^T[d][q] += V^T[d][k] * P^T[k][q]
        o0 = __builtin_amdgcn_mfma_f32_32x32x16_bf16(va0, pb0b, o0, 0, 0, 0);
        o0 = __builtin_amdgcn_mfma_f32_32x32x16_bf16(vb0, pb1b, o0, 0, 0, 0);
        o1 = __builtin_amdgcn_mfma_f32_32x32x16_bf16(va1, pb0b, o1, 0, 0, 0);
        o1 = __builtin_amdgcn_mfma_f32_32x32x16_bf16(vb1, pb1b, o1, 0, 0, 0);

        kf0 = nkf0; kf1 = nkf1; kf2 = nkf2; kf3 = nkf3;
    }

    // ---- merge the 4 waves' partial states (exact, f32) ----
#pragma unroll
    for (int r = 0; r < 16; ++r) {
        int d0 = (r & 3) + 8 * (r >> 2) + 4 * hi;
        Of[wid][lq][d0]      = o0[r];
        Of[wid][lq][32 + d0] = o1[r];
    }
    if (lane < 32) { MLs[wid][0][lq] = m; MLs[wid][1][lq] = l; }
    __syncthreads();

    // 256 threads: thread t -> q = t>>3, d8 = (t&7)*8 (one bf16x8 store each)
    {
        const int tq = threadIdx.x >> 3;
        const int d8 = (threadIdx.x & 7) * 8;
        float m0_ = MLs[0][0][tq], m1_ = MLs[1][0][tq];
        float m2_ = MLs[2][0][tq], m3_ = MLs[3][0][tq];
        float M = fmaxf(fmaxf(m0_, m1_), fmaxf(m2_, m3_));
        float a0 = __expf(m0_ - M), a1 = __expf(m1_ - M);
        float a2 = __expf(m2_ - M), a3 = __expf(m3_ - M);
        float L = MLs[0][1][tq] * a0 + MLs[1][1][tq] * a1
                + MLs[2][1][tq] * a2 + MLs[3][1][tq] * a3;
        float invL = 1.f / L;
        const int b = bh >> 4, h = bh & 15;
        bf16x8 outv;
#pragma unroll
        for (int e = 0; e < 8; ++e) {
            int d = d8 + e;
            float v = a0 * Of[0][tq][d] + a1 * Of[1][tq][d]
                    + a2 * Of[2][tq][d] + a3 * Of[3][tq][d];
            outv[e] = (__bf16)(v * invL);
        }
        *(bf16x8*)&ctx[((size_t)b * S_LEN + q0 + tq) * EMB + h * HD + d8] = outv;
    }
}

// ---------------------------------------------------------------------------
extern "C" void kernel_launch(void* const* d_in, const int* in_sizes, int n_in,
                              void* d_out, int out_size, void* d_ws, size_t ws_size,
                              hipStream_t stream) {
    const float* x  = (const float*)d_in[0];
    const float* Wq = (const float*)d_in[1];
    const float* bq = (const float*)d_in[2];
    const float* Wk = (const float*)d_in[3];
    const float* bk = (const float*)d_in[4];
    const float* Wv = (const float*)d_in[5];
    const float* bv = (const float*)d_in[6];
    const float* Wo = (const float*)d_in[7];
    const float* bo = (const float*)d_in[8];

    char* ws = (char*)d_ws;
    __bf16* xb  = (__bf16*)(ws);                       // 8 MB  (4M bf16)
    __bf16* Wqb = (__bf16*)(ws + ( 8ull << 20));       // 2 MB
    __bf16* Wkb = (__bf16*)(ws + (10ull << 20));
    __bf16* Wvb = (__bf16*)(ws + (12ull << 20));
    __bf16* Wob = (__bf16*)(ws + (14ull << 20));
    __bf16* Qb  = (__bf16*)(ws + (16ull << 20));       // 8 MB [B,H,S,D]
    __bf16* Kb  = (__bf16*)(ws + (24ull << 20));       // 8 MB [B,H,S,D]
    __bf16* Vtb = (__bf16*)(ws + (32ull << 20));       // 8 MB [B,H,D,S]
    __bf16* Cb  = (__bf16*)(ws + (40ull << 20));       // 8 MB [B,S,E]

    // one fused cast (x + 4 weights)
    cast_all<<<8192, 256, 0, stream>>>(x, Wq, Wk, Wv, Wo, xb, Wqb, Wkb, Wvb, Wob);

    // fused QKV projection (z selects Q/K/V), 2-phase dbuf
    gemm_qkv<<<dim3(EMB / 128, M_TOT / 128, 3), 256, 0, stream>>>(
        xb, Wqb, Wkb, Wvb, bq, bk, bv, Qb, Kb, Vtb);

    // flash attention (split-K across waves + f32 merge, defer-max)
    attn_kernel<<<dim3(2048), 256, 0, stream>>>(Qb, Kb, Vtb, Cb);

    // output projection (fp32 out + bias), 2-phase dbuf
    gemm_out<<<dim3(EMB / 128, M_TOT / 128), 256, 0, stream>>>(Cb, Wob, bo, (float*)d_out);
}

// Round 15
// 232.600 us; speedup vs baseline: 1.1068x; 1.0264x over previous
//
#include <hip/hip_runtime.h>
#include <hip/hip_bf16.h>

// Problem constants (fixed by the reference)
#define S_LEN 2048
#define NH    16
#define HD    64
#define EMB   1024
#define BATCH 2
#define M_TOT 4096   // B*S

typedef __attribute__((ext_vector_type(8)))  __bf16   bf16x8;
typedef __attribute__((ext_vector_type(4)))  __bf16   bf16x4;
typedef __attribute__((ext_vector_type(4)))  float    f32x4;
typedef __attribute__((ext_vector_type(16))) float    f32x16;
typedef __attribute__((ext_vector_type(4)))  unsigned u32x4;

// pack two f32 -> one u32 of 2 bf16
static __device__ __forceinline__ unsigned pk2(float a, float b) {
    unsigned short ua = __builtin_bit_cast(unsigned short, (__bf16)a);
    unsigned short ub = __builtin_bit_cast(unsigned short, (__bf16)b);
    return (unsigned)ua | ((unsigned)ub << 16);
}

// ---------------------------------------------------------------------------
// One fused fp32->bf16 cast for x + all 4 weights.
// ---------------------------------------------------------------------------
__global__ __launch_bounds__(256) void cast_all(const float* __restrict__ x,
        const float* __restrict__ wq, const float* __restrict__ wk,
        const float* __restrict__ wv, const float* __restrict__ wo,
        __bf16* __restrict__ xb, __bf16* __restrict__ wqb,
        __bf16* __restrict__ wkb, __bf16* __restrict__ wvb,
        __bf16* __restrict__ wob) {
    int i = blockIdx.x * 256 + threadIdx.x;           // 0 .. 2M-1
    const float* src; __bf16* dst; int j;
    if (i < (1 << 20)) { src = x; dst = xb; j = i; }
    else {
        int t = i - (1 << 20);
        int r = t >> 18;                              // 0..3
        j = t & ((1 << 18) - 1);
        src = (r == 0) ? wq : (r == 1) ? wk : (r == 2) ? wv : wo;
        dst = (r == 0) ? wqb : (r == 1) ? wkb : (r == 2) ? wvb : wob;
    }
    f32x4 v = ((const f32x4*)src)[j];
    bf16x4 o;
    o[0] = (__bf16)v[0]; o[1] = (__bf16)v[1];
    o[2] = (__bf16)v[2]; o[3] = (__bf16)v[3];
    ((bf16x4*)dst)[j] = o;
}

// ---------------------------------------------------------------------------
// FUSED QKV GEMM (under test this round): one block computes the Q, K, V
// 128x128 output tiles from a single staged A-tile (A staged once, reused 3x
// -> 3x MFMA per staging stall, A-traffic /3). 512 threads = 8 waves (2m x 4n),
// each wave owns 64x32 per output. LDS = A + Bq + Bk + Bv = 64KB.
// Grid (8, 32) = 256 blocks = 1/CU exactly (no tail).
// Q,K -> [B,H,S,D]; V -> [B,H,D,S] (transposed) for attention PV A-operand.
// ---------------------------------------------------------------------------
__global__ __launch_bounds__(512) void gemm_qkv(const __bf16* __restrict__ A,
        const __bf16* __restrict__ Wq, const __bf16* __restrict__ Wk,
        const __bf16* __restrict__ Wv,
        const float* __restrict__ bq, const float* __restrict__ bk,
        const float* __restrict__ bv,
        __bf16* __restrict__ Qo, __bf16* __restrict__ Ko, __bf16* __restrict__ Vo) {
    __shared__ __bf16 As [128][64];
    __shared__ __bf16 Bqs[128][64];
    __shared__ __bf16 Bks[128][64];
    __shared__ __bf16 Bvs[128][64];

    const int tid  = threadIdx.x;
    const int wid  = tid >> 6;          // 0..7
    const int lane = tid & 63;
    const int lrow = lane & 15;
    const int lhi  = lane >> 4;
    const int m0 = blockIdx.y * 128;
    const int n0 = blockIdx.x * 128;
    const int wr = wid >> 2, wc = wid & 3;   // 2m x 4n wave grid
    const int lr8 = lane >> 3;
    const int lc8 = (lane & 7) * 8;

    f32x4 aq[4][2], ak[4][2], av[4][2];
#pragma unroll
    for (int i = 0; i < 4; ++i)
#pragma unroll
        for (int j = 0; j < 2; ++j) {
            aq[i][j] = (f32x4){0.f, 0.f, 0.f, 0.f};
            ak[i][j] = (f32x4){0.f, 0.f, 0.f, 0.f};
            av[i][j] = (f32x4){0.f, 0.f, 0.f, 0.f};
        }

    for (int kt = 0; kt < 16; ++kt) {
        const int k0 = kt * 64;
        // stage A + 3 B tiles: each wave fills rows [wid*16, wid*16+16)
#pragma unroll
        for (int t = 0; t < 2; ++t) {
            const int row = wid * 16 + t * 8;
            __builtin_amdgcn_global_load_lds(
                (const __attribute__((address_space(1))) void*)&A [(size_t)(m0 + row + lr8) * EMB + k0 + lc8],
                (__attribute__((address_space(3))) void*)&As[row][0], 16, 0, 0);
            __builtin_amdgcn_global_load_lds(
                (const __attribute__((address_space(1))) void*)&Wq[(size_t)(n0 + row + lr8) * EMB + k0 + lc8],
                (__attribute__((address_space(3))) void*)&Bqs[row][0], 16, 0, 0);
            __builtin_amdgcn_global_load_lds(
                (const __attribute__((address_space(1))) void*)&Wk[(size_t)(n0 + row + lr8) * EMB + k0 + lc8],
                (__attribute__((address_space(3))) void*)&Bks[row][0], 16, 0, 0);
            __builtin_amdgcn_global_load_lds(
                (const __attribute__((address_space(1))) void*)&Wv[(size_t)(n0 + row + lr8) * EMB + k0 + lc8],
                (__attribute__((address_space(3))) void*)&Bvs[row][0], 16, 0, 0);
        }
        __syncthreads();
#pragma unroll
        for (int kk = 0; kk < 2; ++kk) {
            bf16x8 af[4];
#pragma unroll
            for (int i = 0; i < 4; ++i)
                af[i] = *(const bf16x8*)&As[wr * 64 + i * 16 + lrow][kk * 32 + lhi * 8];
            bf16x8 bfr[2];
#pragma unroll
            for (int j = 0; j < 2; ++j)
                bfr[j] = *(const bf16x8*)&Bqs[wc * 32 + j * 16 + lrow][kk * 32 + lhi * 8];
#pragma unroll
            for (int i = 0; i < 4; ++i)
#pragma unroll
                for (int j = 0; j < 2; ++j)
                    aq[i][j] = __builtin_amdgcn_mfma_f32_16x16x32_bf16(af[i], bfr[j], aq[i][j], 0, 0, 0);
#pragma unroll
            for (int j = 0; j < 2; ++j)
                bfr[j] = *(const bf16x8*)&Bks[wc * 32 + j * 16 + lrow][kk * 32 + lhi * 8];
#pragma unroll
            for (int i = 0; i < 4; ++i)
#pragma unroll
                for (int j = 0; j < 2; ++j)
                    ak[i][j] = __builtin_amdgcn_mfma_f32_16x16x32_bf16(af[i], bfr[j], ak[i][j], 0, 0, 0);
#pragma unroll
            for (int j = 0; j < 2; ++j)
                bfr[j] = *(const bf16x8*)&Bvs[wc * 32 + j * 16 + lrow][kk * 32 + lhi * 8];
#pragma unroll
            for (int i = 0; i < 4; ++i)
#pragma unroll
                for (int j = 0; j < 2; ++j)
                    av[i][j] = __builtin_amdgcn_mfma_f32_16x16x32_bf16(af[i], bfr[j], av[i][j], 0, 0, 0);
        }
        __syncthreads();
    }

    // Epilogue x3. C/D layout: col = lane&15, row = (lane>>4)*4 + reg.
#define QKV_EPI(ACC, OUTP, BIASP, ISV)                                            \
    _Pragma("unroll")                                                             \
    for (int i = 0; i < 4; ++i)                                                   \
        _Pragma("unroll")                                                         \
        for (int j = 0; j < 2; ++j)                                               \
            _Pragma("unroll")                                                     \
            for (int jj = 0; jj < 4; ++jj) {                                      \
                int row = m0 + wr * 64 + i * 16 + lhi * 4 + jj;                   \
                int col = n0 + wc * 32 + j * 16 + lrow;                           \
                float v = ACC[i][j][jj] + BIASP[col];                             \
                int b = row >> 11, s = row & (S_LEN - 1);                         \
                int h = col >> 6,  d = col & (HD - 1);                            \
                size_t idx = (ISV)                                                \
                    ? ((size_t)(b * NH + h) * HD + d) * S_LEN + s                 \
                    : ((size_t)(b * NH + h) * S_LEN + s) * HD + d;                \
                OUTP[idx] = (__bf16)v;                                            \
            }
    QKV_EPI(aq, Qo, bq, 0)
    QKV_EPI(ak, Ko, bk, 0)
    QKV_EPI(av, Vo, bv, 1)
#undef QKV_EPI
}

// ---------------------------------------------------------------------------
// 2-phase double-buffered GEMM body (r10-verified).
// ---------------------------------------------------------------------------
#define GEMM_STAGE(Abuf, Bbuf, Asrc, Bsrc, k0)                                            \
    _Pragma("unroll")                                                                     \
    for (int t = 0; t < 4; ++t) {                                                         \
        const int row = wid * 32 + t * 8;                                                 \
        __builtin_amdgcn_global_load_lds(                                                 \
            (const __attribute__((address_space(1))) void*)&Asrc[(size_t)(m0 + row + lr8) * EMB + (k0) + lc8], \
            (__attribute__((address_space(3))) void*)&Abuf[row][0], 16, 0, 0);            \
        __builtin_amdgcn_global_load_lds(                                                 \
            (const __attribute__((address_space(1))) void*)&Bsrc[(size_t)(n0 + row + lr8) * EMB + (k0) + lc8], \
            (__attribute__((address_space(3))) void*)&Bbuf[row][0], 16, 0, 0);            \
    }

#define GEMM_COMPUTE(Abuf, Bbuf)                                                          \
    _Pragma("unroll")                                                                     \
    for (int kk = 0; kk < 2; ++kk) {                                                      \
        bf16x8 af[4], bfr[4];                                                             \
        _Pragma("unroll")                                                                 \
        for (int i = 0; i < 4; ++i)                                                       \
            af[i] = *(const bf16x8*)&Abuf[wr * 64 + i * 16 + lrow][kk * 32 + lhi * 8];    \
        _Pragma("unroll")                                                                 \
        for (int j = 0; j < 4; ++j)                                                       \
            bfr[j] = *(const bf16x8*)&Bbuf[wc * 64 + j * 16 + lrow][kk * 32 + lhi * 8];   \
        _Pragma("unroll")                                                                 \
        for (int i = 0; i < 4; ++i)                                                       \
            _Pragma("unroll")                                                             \
            for (int j = 0; j < 4; ++j)                                                   \
                acc[i][j] = __builtin_amdgcn_mfma_f32_16x16x32_bf16(af[i], bfr[j], acc[i][j], 0, 0, 0); \
    }

// ---------------------------------------------------------------------------
// Output projection: out[4096,1024] fp32 = ctx bf16 @ Wo^T + bo (2-phase dbuf)
// ---------------------------------------------------------------------------
__global__ __launch_bounds__(256) void gemm_out(const __bf16* __restrict__ A,
        const __bf16* __restrict__ Bw, const float* __restrict__ bias,
        float* __restrict__ outp) {
    __shared__ __bf16 As0[128][64], As1[128][64];
    __shared__ __bf16 Bs0[128][64], Bs1[128][64];

    const int tid  = threadIdx.x;
    const int wid  = tid >> 6;
    const int lane = tid & 63;
    const int lrow = lane & 15;
    const int lhi  = lane >> 4;
    const int m0 = blockIdx.y * 128;
    const int n0 = blockIdx.x * 128;
    const int wr = wid >> 1, wc = wid & 1;
    const int lr8 = lane >> 3;
    const int lc8 = (lane & 7) * 8;

    f32x4 acc[4][4];
#pragma unroll
    for (int i = 0; i < 4; ++i)
#pragma unroll
        for (int j = 0; j < 4; ++j)
            acc[i][j] = (f32x4){0.f, 0.f, 0.f, 0.f};

    GEMM_STAGE(As0, Bs0, A, Bw, 0)
    __syncthreads();
    for (int kt = 0; kt < 16; kt += 2) {
        GEMM_STAGE(As1, Bs1, A, Bw, (kt + 1) * 64)
        GEMM_COMPUTE(As0, Bs0)
        __syncthreads();
        if (kt + 2 < 16) { GEMM_STAGE(As0, Bs0, A, Bw, (kt + 2) * 64) }
        GEMM_COMPUTE(As1, Bs1)
        __syncthreads();
    }

#pragma unroll
    for (int i = 0; i < 4; ++i)
#pragma unroll
        for (int j = 0; j < 4; ++j)
#pragma unroll
            for (int jj = 0; jj < 4; ++jj) {
                int row = m0 + wr * 64 + i * 16 + lhi * 4 + jj;
                int col = n0 + wc * 64 + j * 16 + lrow;
                outp[(size_t)row * EMB + col] = acc[i][j][jj] + bias[col];
            }
}

// ---------------------------------------------------------------------------
// Flash attention — EXACT r10-verified kernel (passed, absmax 0.0078):
// swapped-QK^T 32x32, split-K across waves, f32 merge, defer-max, shfl_xor
// exchanges (DS-pipe). The r12 PSWAP experiment had the permlane operand
// order backwards (v_permlane32_swap_b32 swaps vdst.lo with src.hi, not the
// mapping I assumed) -> halves crossed -> absmax 1.28. Reverted; re-introduce
// with corrected order once the fused QKV is validated.
// ---------------------------------------------------------------------------
__global__ __launch_bounds__(256) void attn_kernel(const __bf16* __restrict__ Q,
        const __bf16* __restrict__ K, const __bf16* __restrict__ Vt,
        __bf16* __restrict__ ctx) {
    __shared__ float Of[4][32][65];      // per-wave partial O^T (f32), padded
    __shared__ float MLs[4][2][32];      // per-wave (m, l) per q-row

    const int wid  = threadIdx.x >> 6;
    const int lane = threadIdx.x & 63;
    const int lq   = lane & 31;          // q-column owned by this lane
    const int hi   = lane >> 5;          // half-select
    const int bid  = blockIdx.x;
    const int xcd  = bid & 7;
    const int idx  = bid >> 3;           // 0..255
    const int qt   = 63 - (idx & 63);    // big tiles first (tail drain)
    const int bh   = xcd + 8 * (idx >> 6);   // 0..31
    const int q0   = qt * 32;

    const __bf16* Qh = Q  + (size_t)bh * S_LEN * HD;
    const __bf16* Kh = K  + (size_t)bh * S_LEN * HD;
    const __bf16* Vh = Vt + (size_t)bh * HD * S_LEN;

    // Q B-frag (col=lq, k-elems hi*8..+8 per 16-d slice), pre-scaled by 2^-3
    bf16x8 qf[4];
#pragma unroll
    for (int ds = 0; ds < 4; ++ds) {
        bf16x8 t = *(const bf16x8*)&Qh[(size_t)(q0 + lq) * HD + ds * 16 + hi * 8];
#pragma unroll
        for (int j = 0; j < 8; ++j) qf[ds][j] = (__bf16)((float)t[j] * 0.125f);
    }

    f32x16 o0, o1;                       // O^T accum, d-blocks 0..31 / 32..63
#pragma unroll
    for (int r = 0; r < 16; ++r) { o0[r] = 0.f; o1[r] = 0.f; }
    float m = -1e30f, l = 0.f;

    const int nkt = qt + 1;              // causal: 32-key tiles total

    // prologue: K frags for this wave's first tile (kt = wid)
    bf16x8 kf0, kf1, kf2, kf3;
    if (wid < nkt) {
        const __bf16* kp = &Kh[(size_t)(wid * 32 + lq) * HD + hi * 8];
        kf0 = *(const bf16x8*)(kp);      kf1 = *(const bf16x8*)(kp + 16);
        kf2 = *(const bf16x8*)(kp + 32); kf3 = *(const bf16x8*)(kp + 48);
    }

    for (int kt = wid; kt < nkt; kt += 4) {
        const int kk0 = kt * 32;

        // current V loads (consumed after softmax — latency hidden)
        bf16x8 va0 = *(const bf16x8*)&Vh[(size_t)lq * S_LEN + kk0 + hi * 8];
        bf16x8 vb0 = *(const bf16x8*)&Vh[(size_t)lq * S_LEN + kk0 + 16 + hi * 8];
        bf16x8 va1 = *(const bf16x8*)&Vh[(size_t)(32 + lq) * S_LEN + kk0 + hi * 8];
        bf16x8 vb1 = *(const bf16x8*)&Vh[(size_t)(32 + lq) * S_LEN + kk0 + 16 + hi * 8];

        // prefetch NEXT K tile for this wave (kt+4; clamped on last)
        const int nk0 = (kt + 4 < nkt ? kt + 4 : kt) * 32;
        bf16x8 nkf0, nkf1, nkf2, nkf3;
        {
            const __bf16* kp = &Kh[(size_t)(nk0 + lq) * HD + hi * 8];
            nkf0 = *(const bf16x8*)(kp);      nkf1 = *(const bf16x8*)(kp + 16);
            nkf2 = *(const bf16x8*)(kp + 32); nkf3 = *(const bf16x8*)(kp + 48);
        }

        // QK^T (swapped): S^T = K-frag x Q-frag
        f32x16 s;
#pragma unroll
        for (int r = 0; r < 16; ++r) s[r] = 0.f;
        s = __builtin_amdgcn_mfma_f32_32x32x16_bf16(kf0, qf[0], s, 0, 0, 0);
        s = __builtin_amdgcn_mfma_f32_32x32x16_bf16(kf1, qf[1], s, 0, 0, 0);
        s = __builtin_amdgcn_mfma_f32_32x32x16_bf16(kf2, qf[2], s, 0, 0, 0);
        s = __builtin_amdgcn_mfma_f32_32x32x16_bf16(kf3, qf[3], s, 0, 0, 0);

        // causal mask — only the diagonal tile (wave-uniform branch)
        if (kk0 == q0) {
#pragma unroll
            for (int r = 0; r < 16; ++r) {
                int keyl = (r & 3) + 8 * (r >> 2) + 4 * hi;
                s[r] = (keyl <= lq) ? s[r] : -1e30f;
            }
        }

        // row max: 15 in-lane + cross-half exchange
        float pm = s[0];
#pragma unroll
        for (int r = 1; r < 16; ++r) pm = fmaxf(pm, s[r]);
        pm = fmaxf(pm, __shfl_xor(pm, 32));

        // T13 defer-max: only rescale when running max grew by > 8
        if (!__all(pm - m <= 8.f)) {
            float mn = fmaxf(m, pm);
            float f  = __expf(m - mn);
            l *= f;
#pragma unroll
            for (int r = 0; r < 16; ++r) { o0[r] *= f; o1[r] *= f; }
            m = mn;
        }

        float ps = 0.f;
#pragma unroll
        for (int r = 0; r < 16; ++r) { s[r] = __expf(s[r] - m); ps += s[r]; }
        ps += __shfl_xor(ps, 32);
        l += ps;

        // pack P to bf16 pairs
        unsigned w0 = pk2(s[0],  s[1]),  w1 = pk2(s[2],  s[3]);
        unsigned w2 = pk2(s[4],  s[5]),  w3 = pk2(s[6],  s[7]);
        unsigned w4 = pk2(s[8],  s[9]),  w5 = pk2(s[10], s[11]);
        unsigned w6 = pk2(s[12], s[13]), w7 = pk2(s[14], s[15]);

        // cross-half redistribution into PV B-frag (branchless cndmask)
        unsigned e0 = (unsigned)__shfl_xor((int)(hi ? w0 : w2), 32);
        unsigned e1 = (unsigned)__shfl_xor((int)(hi ? w1 : w3), 32);
        unsigned e2 = (unsigned)__shfl_xor((int)(hi ? w4 : w6), 32);
        unsigned e3 = (unsigned)__shfl_xor((int)(hi ? w5 : w7), 32);
        u32x4 pb0, pb1;
        pb0[0] = hi ? e0 : w0;  pb0[1] = hi ? e1 : w1;
        pb0[2] = hi ? w2 : e0;  pb0[3] = hi ? w3 : e1;
        pb1[0] = hi ? e2 : w4;  pb1[1] = hi ? e3 : w5;
        pb1[2] = hi ? w6 : e2;  pb1[3] = hi ? w7 : e3;
        bf16x8 pb0b = __builtin_bit_cast(bf16x8, pb0);
        bf16x8 pb1b = __builtin_bit_cast(bf16x8, pb1);

        // PV: O^T[d][q] += V^T[d][k] * P^T[k][q]
        o0 = __builtin_amdgcn_mfma_f32_32x32x16_bf16(va0, pb0b, o0, 0, 0, 0);
        o0 = __builtin_amdgcn_mfma_f32_32x32x16_bf16(vb0, pb1b, o0, 0, 0, 0);
        o1 = __builtin_amdgcn_mfma_f32_32x32x16_bf16(va1, pb0b, o1, 0, 0, 0);
        o1 = __builtin_amdgcn_mfma_f32_32x32x16_bf16(vb1, pb1b, o1, 0, 0, 0);

        kf0 = nkf0; kf1 = nkf1; kf2 = nkf2; kf3 = nkf3;
    }

    // ---- merge the 4 waves' partial states (exact, f32) ----
#pragma unroll
    for (int r = 0; r < 16; ++r) {
        int d0 = (r & 3) + 8 * (r >> 2) + 4 * hi;
        Of[wid][lq][d0]      = o0[r];
        Of[wid][lq][32 + d0] = o1[r];
    }
    if (lane < 32) { MLs[wid][0][lq] = m; MLs[wid][1][lq] = l; }
    __syncthreads();

    // 256 threads: thread t -> q = t>>3, d8 = (t&7)*8 (one bf16x8 store each)
    {
        const int tq = threadIdx.x >> 3;
        const int d8 = (threadIdx.x & 7) * 8;
        float m0_ = MLs[0][0][tq], m1_ = MLs[1][0][tq];
        float m2_ = MLs[2][0][tq], m3_ = MLs[3][0][tq];
        float M = fmaxf(fmaxf(m0_, m1_), fmaxf(m2_, m3_));
        float a0 = __expf(m0_ - M), a1 = __expf(m1_ - M);
        float a2 = __expf(m2_ - M), a3 = __expf(m3_ - M);
        float L = MLs[0][1][tq] * a0 + MLs[1][1][tq] * a1
                + MLs[2][1][tq] * a2 + MLs[3][1][tq] * a3;
        float invL = 1.f / L;
        const int b = bh >> 4, h = bh & 15;
        bf16x8 outv;
#pragma unroll
        for (int e = 0; e < 8; ++e) {
            int d = d8 + e;
            float v = a0 * Of[0][tq][d] + a1 * Of[1][tq][d]
                    + a2 * Of[2][tq][d] + a3 * Of[3][tq][d];
            outv[e] = (__bf16)(v * invL);
        }
        *(bf16x8*)&ctx[((size_t)b * S_LEN + q0 + tq) * EMB + h * HD + d8] = outv;
    }
}

// ---------------------------------------------------------------------------
extern "C" void kernel_launch(void* const* d_in, const int* in_sizes, int n_in,
                              void* d_out, int out_size, void* d_ws, size_t ws_size,
                              hipStream_t stream) {
    const float* x  = (const float*)d_in[0];
    const float* Wq = (const float*)d_in[1];
    const float* bq = (const float*)d_in[2];
    const float* Wk = (const float*)d_in[3];
    const float* bk = (const float*)d_in[4];
    const float* Wv = (const float*)d_in[5];
    const float* bv = (const float*)d_in[6];
    const float* Wo = (const float*)d_in[7];
    const float* bo = (const float*)d_in[8];

    char* ws = (char*)d_ws;
    __bf16* xb  = (__bf16*)(ws);                       // 8 MB  (4M bf16)
    __bf16* Wqb = (__bf16*)(ws + ( 8ull << 20));       // 2 MB
    __bf16* Wkb = (__bf16*)(ws + (10ull << 20));
    __bf16* Wvb = (__bf16*)(ws + (12ull << 20));
    __bf16* Wob = (__bf16*)(ws + (14ull << 20));
    __bf16* Qb  = (__bf16*)(ws + (16ull << 20));       // 8 MB [B,H,S,D]
    __bf16* Kb  = (__bf16*)(ws + (24ull << 20));       // 8 MB [B,H,S,D]
    __bf16* Vtb = (__bf16*)(ws + (32ull << 20));       // 8 MB [B,H,D,S]
    __bf16* Cb  = (__bf16*)(ws + (40ull << 20));       // 8 MB [B,S,E]

    // one fused cast (x + 4 weights)
    cast_all<<<8192, 256, 0, stream>>>(x, Wq, Wk, Wv, Wo, xb, Wqb, Wkb, Wvb, Wob);

    // fused QKV projection: one block does Q,K,V tiles from one A-tile
    gemm_qkv<<<dim3(EMB / 128, M_TOT / 128), 512, 0, stream>>>(
        xb, Wqb, Wkb, Wvb, bq, bk, bv, Qb, Kb, Vtb);

    // flash attention (r10-verified inner loop; split-K + f32 merge)
    attn_kernel<<<dim3(2048), 256, 0, stream>>>(Qb, Kb, Vtb, Cb);

    // output projection (fp32 out + bias), 2-phase dbuf
    gemm_out<<<dim3(EMB / 128, M_TOT / 128), 256, 0, stream>>>(Cb, Wob, bo, (float*)d_out);
}